// Round 2
// baseline (571.832 us; speedup 1.0000x reference)
//
#include <hip/hip_runtime.h>

#define B_ 4
#define C_ 192
#define S_ 64
#define L_ 512

typedef _Float16 h4 __attribute__((ext_vector_type(4)));
typedef unsigned int uint_t;

// ---------------- K0: transpose weights, convert f32 -> f16, into ws -------
// wvT[c*192+o] = wv[o][c] = W[(1+C+o)*C + c];  woT[o*192+p] = Wo[p*C + o]
__global__ __launch_bounds__(512) void k_prep(
    const float* __restrict__ W,
    const float* __restrict__ Wo,
    _Float16* __restrict__ wvT,
    _Float16* __restrict__ woT)
{
    int n = blockIdx.x * 512 + threadIdx.x;
    if (n < C_ * C_) {
        int c = n / C_, o = n % C_;
        wvT[n] = (_Float16)W[(1 + C_ + o) * C_ + c];
    } else {
        int m = n - C_ * C_;
        int o = m / C_, p = m % C_;
        woT[m] = (_Float16)Wo[p * C_ + o];
    }
}

// ---------------- K1: per (b,s): softmax(wq@Q) -> kbar -> context ----------
__global__ __launch_bounds__(512) void k_ctx(
    const float* __restrict__ Q,
    const float* __restrict__ K,
    const float* __restrict__ W,
    const float* __restrict__ Bias,
    float* __restrict__ ctx_out)
{
    __shared__ float sm_wq[C_];
    __shared__ float sm_sc[L_];
    __shared__ float sm_kbar[C_];
    __shared__ float sm_red[8];
    __shared__ float sm_red2[8];

    const int t = threadIdx.x;
    const int b = blockIdx.x >> 6, s = blockIdx.x & 63;
    const int lane = t & 63, w = t >> 6;

    if (t < C_) sm_wq[t] = W[t];   // wq = row 0
    __syncthreads();

    // ---- q projection: thread t owns l = t (bq dropped: softmax-invariant)
    const float* qp = Q + ((size_t)(b * C_) * S_ + s) * L_ + t;
    float q = 0.f;
    for (int c = 0; c < C_; ++c) q += sm_wq[c] * qp[(size_t)c * (S_ * L_)];

    // ---- softmax over 512 values
    float m = q;
#pragma unroll
    for (int off = 32; off >= 1; off >>= 1) m = fmaxf(m, __shfl_down(m, off));
    if (lane == 0) sm_red[w] = m;
    __syncthreads();
    float bm = sm_red[0];
#pragma unroll
    for (int i = 1; i < 8; ++i) bm = fmaxf(bm, sm_red[i]);
    float e = __expf(q - bm);
    float sum = e;
#pragma unroll
    for (int off = 32; off >= 1; off >>= 1) sum += __shfl_down(sum, off);
    if (lane == 0) sm_red2[w] = sum;
    __syncthreads();
    float tot = 0.f;
#pragma unroll
    for (int i = 0; i < 8; ++i) tot += sm_red2[i];
    sm_sc[t] = e / tot;
    __syncthreads();

    // ---- kbar[c] = sum_l K[c,l]*p[l]   (wave w handles c = w + 8*ii)
    float sc[8];
#pragma unroll
    for (int i = 0; i < 8; ++i) sc[i] = sm_sc[i * 64 + lane];
    const float* kp = K + ((size_t)(b * C_) * S_ + s) * L_ + lane;
    for (int ii = 0; ii < 24; ++ii) {
        int c = w + 8 * ii;
        const float* kc = kp + (size_t)c * (S_ * L_);
        float p = 0.f;
#pragma unroll
        for (int i = 0; i < 8; ++i) p += sc[i] * kc[i * 64];
#pragma unroll
        for (int off = 32; off >= 1; off >>= 1) p += __shfl_down(p, off);
        if (lane == 0) sm_kbar[c] = p;
    }
    __syncthreads();

    // ---- ctx[o] = wk[o,:]@kbar + bk[o]  (row reads coalesced along c)
    float kb[3];
#pragma unroll
    for (int i = 0; i < 3; ++i) kb[i] = sm_kbar[i * 64 + lane];
    for (int ii = 0; ii < 24; ++ii) {
        int o = w + 8 * ii;
        const float* wr = W + (1 + o) * C_ + lane;
        float p = 0.f;
#pragma unroll
        for (int i = 0; i < 3; ++i) p += kb[i] * wr[i * 64];
#pragma unroll
        for (int off = 32; off >= 1; off >>= 1) p += __shfl_down(p, off);
        if (lane == 0) ctx_out[(b * S_ + s) * C_ + o] = p + Bias[1 + o];
    }
}

// ---------------- K2: per (b,s): out = wo @ (ctx * relu(wv @ V + bv)) + bo --
// 512 thr: tx = t&31 owns l = l0 + tx*4 + k (k<4); gy = t>>5 owns o = gy*12+j
// LDS: weight c-tile (32x192 f16) + u chunk (192x128 f16). 48 acc regs/thread.
__global__ __launch_bounds__(512) void k_main(
    const float* __restrict__ V,
    const _Float16* __restrict__ wvT,
    const _Float16* __restrict__ woT,
    const float* __restrict__ ctx_in,
    const float* __restrict__ Bias,
    const float* __restrict__ OBias,
    float* __restrict__ Out)
{
    __shared__ __attribute__((aligned(16))) _Float16 sm_w[32 * C_];     // 12 KB
    __shared__ __attribute__((aligned(16))) _Float16 sm_u[C_ * 128];    // 48 KB
    __shared__ float sm_ctx[C_];

    const int t = threadIdx.x;
    const int b = blockIdx.x >> 6, s = blockIdx.x & 63;
    const int tx = t & 31;
    const int gy = t >> 5;   // 0..15

    if (t < C_) sm_ctx[t] = ctx_in[(b * S_ + s) * C_ + t];

    float bvr[12], bor[12];
#pragma unroll
    for (int j = 0; j < 12; ++j) {
        bvr[j] = Bias[1 + C_ + gy * 12 + j];
        bor[j] = OBias[gy * 12 + j];
    }
    __syncthreads();

    const uint_t* wv_u = (const uint_t*)wvT;
    const uint_t* wo_u = (const uint_t*)woT;

    for (int chunk = 0; chunk < 4; ++chunk) {
        const int l0 = chunk * 128;

        // ================= C1: v = wv @ Vin (+bv), u = ctx*relu(v) =========
        float acc[48];
#pragma unroll
        for (int j = 0; j < 12; ++j)
#pragma unroll
            for (int k = 0; k < 4; ++k) acc[j * 4 + k] = bvr[j];

        for (int ct = 0; ct < 6; ++ct) {
            __syncthreads();
            {   // stage wvT rows c in [32ct, 32ct+32): 3072 dwords
                uint_t* dst = (uint_t*)sm_w;
                const uint_t* src = wv_u + ct * 3072;
#pragma unroll
                for (int i = 0; i < 6; ++i) dst[t + 512 * i] = src[t + 512 * i];
            }
            __syncthreads();
            const float* vp =
                V + (((size_t)(b * C_ + ct * 32) * S_ + s) * L_) + l0 + tx * 4;
#pragma unroll 4
            for (int cl = 0; cl < 32; ++cl) {
                float4 vv = *(const float4*)vp;        // 16B coalesced
                vp += S_ * L_;
                const _Float16* wr = sm_w + cl * C_ + gy * 12;
                h4 w0 = *(const h4*)(wr);
                h4 w1 = *(const h4*)(wr + 4);
                h4 w2 = *(const h4*)(wr + 8);
                _Float16 wf[12] = {w0.x, w0.y, w0.z, w0.w,
                                   w1.x, w1.y, w1.z, w1.w,
                                   w2.x, w2.y, w2.z, w2.w};
#pragma unroll
                for (int j = 0; j < 12; ++j) {
                    float wj = (float)wf[j];
                    acc[j * 4 + 0] += wj * vv.x;
                    acc[j * 4 + 1] += wj * vv.y;
                    acc[j * 4 + 2] += wj * vv.z;
                    acc[j * 4 + 3] += wj * vv.w;
                }
            }
        }

        // write u = ctx * relu(v) as f16
#pragma unroll
        for (int j = 0; j < 12; ++j) {
            const int o = gy * 12 + j;
            const float cx = sm_ctx[o];
            h4 uu;
            uu.x = (_Float16)(cx * fmaxf(acc[j * 4 + 0], 0.f));
            uu.y = (_Float16)(cx * fmaxf(acc[j * 4 + 1], 0.f));
            uu.z = (_Float16)(cx * fmaxf(acc[j * 4 + 2], 0.f));
            uu.w = (_Float16)(cx * fmaxf(acc[j * 4 + 3], 0.f));
            *(h4*)(sm_u + o * 128 + tx * 4) = uu;
        }
        __syncthreads();

        // ================= C2: out = wo @ u + bo ===========================
        float acc2[48];
#pragma unroll
        for (int j = 0; j < 12; ++j)
#pragma unroll
            for (int k = 0; k < 4; ++k) acc2[j * 4 + k] = bor[j];

        for (int ot = 0; ot < 6; ++ot) {
            __syncthreads();
            {   // stage woT rows o in [32ot, 32ot+32)
                uint_t* dst = (uint_t*)sm_w;
                const uint_t* src = wo_u + ot * 3072;
#pragma unroll
                for (int i = 0; i < 6; ++i) dst[t + 512 * i] = src[t + 512 * i];
            }
            __syncthreads();
#pragma unroll 4
            for (int ol = 0; ol < 32; ++ol) {
                const int o = ot * 32 + ol;
                h4 uu = *(const h4*)(sm_u + o * 128 + tx * 4);
                float u0 = (float)uu.x, u1 = (float)uu.y;
                float u2 = (float)uu.z, u3 = (float)uu.w;
                const _Float16* wr = sm_w + ol * C_ + gy * 12;
                h4 w0 = *(const h4*)(wr);
                h4 w1 = *(const h4*)(wr + 4);
                h4 w2 = *(const h4*)(wr + 8);
                _Float16 wf[12] = {w0.x, w0.y, w0.z, w0.w,
                                   w1.x, w1.y, w1.z, w1.w,
                                   w2.x, w2.y, w2.z, w2.w};
#pragma unroll
                for (int j = 0; j < 12; ++j) {
                    float wj = (float)wf[j];
                    acc2[j * 4 + 0] += wj * u0;
                    acc2[j * 4 + 1] += wj * u1;
                    acc2[j * 4 + 2] += wj * u2;
                    acc2[j * 4 + 3] += wj * u3;
                }
            }
        }

        // store 4 consecutive f32 per (j): one dwordx4 per store
#pragma unroll
        for (int j = 0; j < 12; ++j) {
            const int p = gy * 12 + j;
            float4 ov;
            ov.x = acc2[j * 4 + 0];
            ov.y = acc2[j * 4 + 1];
            ov.z = acc2[j * 4 + 2];
            ov.w = acc2[j * 4 + 3];
            *(float4*)(Out + ((size_t)(b * C_ + p) * S_ + s) * L_ + l0 + tx * 4) = ov;
        }
        // next chunk's first __syncthreads() protects sm_u / sm_w reuse
    }
}

extern "C" void kernel_launch(void* const* d_in, const int* in_sizes, int n_in,
                              void* d_out, int out_size, void* d_ws, size_t ws_size,
                              hipStream_t stream) {
    const float* Q  = (const float*)d_in[0];
    const float* K  = (const float*)d_in[1];
    const float* V  = (const float*)d_in[2];
    const float* W  = (const float*)d_in[3];
    const float* Bi = (const float*)d_in[4];
    const float* Wo = (const float*)d_in[5];
    const float* Bo = (const float*)d_in[6];
    float* Out = (float*)d_out;

    char* ws = (char*)d_ws;
    _Float16* wvT = (_Float16*)(ws);               // 73728 B
    _Float16* woT = (_Float16*)(ws + 73728);       // 73728 B
    float*    ctx = (float*)(ws + 147456);         // 196608 B  (total 344 KB)

    k_prep<<<dim3((2 * C_ * C_) / 512), dim3(512), 0, stream>>>(W, Wo, wvT, woT);
    k_ctx <<<dim3(B_ * S_),             dim3(512), 0, stream>>>(Q, K, W, Bi, ctx);
    k_main<<<dim3(B_ * S_),             dim3(512), 0, stream>>>(V, wvT, woT, ctx, Bi, Bo, Out);
}

// Round 3
// 355.147 us; speedup vs baseline: 1.6101x; 1.6101x over previous
//
#include <hip/hip_runtime.h>

#define B_ 4
#define C_ 192
#define S_ 64
#define L_ 512

typedef _Float16 h8 __attribute__((ext_vector_type(8)));
typedef _Float16 h4 __attribute__((ext_vector_type(4)));
typedef _Float16 h2 __attribute__((ext_vector_type(2)));
typedef float f4 __attribute__((ext_vector_type(4)));

// swizzle: phys f16 index within [l][c] tile (64 x 192), stride 192, group-XOR
__device__ __forceinline__ int swz_l(int l) { return ((l >> 2) ^ l) & 7; }

// ---------------- K0: weights f32 -> f16 copies + f32 bias copies ----------
__global__ __launch_bounds__(512) void k_prep(
    const float* __restrict__ W, const float* __restrict__ Bi,
    const float* __restrict__ Wo, const float* __restrict__ Bo,
    _Float16* __restrict__ wvh, _Float16* __restrict__ woh,
    float* __restrict__ bvf, float* __restrict__ bof)
{
    int n = blockIdx.x * 512 + threadIdx.x;
    if (n < 36864)       wvh[n] = (_Float16)W[37056 + n];        // rows 1+C..1+2C-1
    else if (n < 73728)  woh[n - 36864] = (_Float16)Wo[n - 36864];
    else if (n < 73920)  bvf[n - 73728] = Bi[1 + C_ + (n - 73728)];
    else if (n < 74112)  bof[n - 73920] = Bo[n - 73920];
}

// ---------------- K1: q = wq@Q, softmax over l -> p ------------------------
__global__ __launch_bounds__(512) void k1_qsoft(
    const float* __restrict__ Q, const float* __restrict__ W,
    float* __restrict__ pbuf)
{
    __shared__ float sm_wq[C_];
    __shared__ float sm_red[8];
    __shared__ float sm_red2[8];

    const int t = threadIdx.x;
    const int b = blockIdx.x >> 6, s = blockIdx.x & 63;
    const int lane = t & 63, w = t >> 6;

    if (t < C_) sm_wq[t] = W[t];   // wq = row 0 (bq dropped: softmax-invariant)
    __syncthreads();

    const float* qp = Q + ((size_t)(b * C_) * S_ + s) * L_ + t;
    float a0 = 0.f, a1 = 0.f, a2 = 0.f, a3 = 0.f;
    for (int c = 0; c < C_; c += 4) {
        a0 += sm_wq[c + 0] * qp[(size_t)(c + 0) * (S_ * L_)];
        a1 += sm_wq[c + 1] * qp[(size_t)(c + 1) * (S_ * L_)];
        a2 += sm_wq[c + 2] * qp[(size_t)(c + 2) * (S_ * L_)];
        a3 += sm_wq[c + 3] * qp[(size_t)(c + 3) * (S_ * L_)];
    }
    float q = (a0 + a1) + (a2 + a3);

    float m = q;
#pragma unroll
    for (int off = 32; off >= 1; off >>= 1) m = fmaxf(m, __shfl_down(m, off));
    if (lane == 0) sm_red[w] = m;
    __syncthreads();
    float bm = sm_red[0];
#pragma unroll
    for (int i = 1; i < 8; ++i) bm = fmaxf(bm, sm_red[i]);
    float e = __expf(q - bm);
    float sum = e;
#pragma unroll
    for (int off = 32; off >= 1; off >>= 1) sum += __shfl_down(sum, off);
    if (lane == 0) sm_red2[w] = sum;
    __syncthreads();
    float tot = 0.f;
#pragma unroll
    for (int i = 0; i < 8; ++i) tot += sm_red2[i];

    pbuf[(size_t)blockIdx.x * 512 + t] = e / tot;
}

// ---------------- K2: kbar[bs,c] = sum_l K[b,c,s,l] * p[bs,l] --------------
// grid = 256*6; block 256 (4 waves, 8 rows each). p chunk per lane matches K chunk.
__global__ __launch_bounds__(256) void k2_kbar(
    const float* __restrict__ K, const float* __restrict__ pbuf,
    float* __restrict__ kbar)
{
    const int t = threadIdx.x;
    const int bs = blockIdx.x / 6;
    const int cg = blockIdx.x - bs * 6;
    const int b = bs >> 6, s = bs & 63;
    const int wv = t >> 6, lane = t & 63;

    const f4* pp = (const f4*)(pbuf + (size_t)bs * 512);
    f4 p0 = pp[lane], p1 = pp[lane + 64];

    for (int r = 0; r < 8; ++r) {
        int c = cg * 32 + wv * 8 + r;
        const f4* kp = (const f4*)(K + ((size_t)(b * C_ + c) * S_ + s) * L_);
        f4 x0 = kp[lane], x1 = kp[lane + 64];
        float d = x0[0]*p0[0] + x0[1]*p0[1] + x0[2]*p0[2] + x0[3]*p0[3]
                + x1[0]*p1[0] + x1[1]*p1[1] + x1[2]*p1[2] + x1[3]*p1[3];
#pragma unroll
        for (int off = 32; off >= 1; off >>= 1) d += __shfl_down(d, off);
        if (lane == 0) kbar[(size_t)bs * C_ + c] = d;
    }
}

// ---------------- K3: ctx[bs,o] = wk[o,:] @ kbar[bs,:] + bk[o] -------------
__global__ __launch_bounds__(192) void k3_ctx(
    const float* __restrict__ W, const float* __restrict__ Bi,
    const float* __restrict__ kbar, float* __restrict__ ctxb)
{
    __shared__ float kb[C_];
    const int t = threadIdx.x, bs = blockIdx.x;
    kb[t] = kbar[(size_t)bs * C_ + t];
    __syncthreads();
    const float* wr = W + (size_t)(1 + t) * C_;
    float a0 = 0.f, a1 = 0.f, a2 = 0.f, a3 = 0.f;
    for (int c = 0; c < C_; c += 4) {
        a0 += wr[c + 0] * kb[c + 0];
        a1 += wr[c + 1] * kb[c + 1];
        a2 += wr[c + 2] * kb[c + 2];
        a3 += wr[c + 3] * kb[c + 3];
    }
    ctxb[(size_t)bs * C_ + t] = (a0 + a1) + (a2 + a3) + Bi[1 + t];
}

// ---------------- K4: MFMA main: out = wo @ (ctx*relu(wv@V+bv)) + bo -------
// grid = 256*(L/64) = 2048 blocks; 512 thr (8 waves). Per block: 192x64 tile.
// GEMM1 D[o,l]: A=Wv[o][c] (sm_w), B=V^T (sm_v [l][c] swizzled). 16x16x32 f16.
// GEMM2 D[l,p]: A=u [l][o] (sm_u swizzled), B=Wo[p][o] (sm_w).
__global__ __launch_bounds__(512, 4) void k_main(
    const float* __restrict__ V,
    const _Float16* __restrict__ wvh,
    const _Float16* __restrict__ woh,
    const float* __restrict__ ctxb,
    const float* __restrict__ bvf,
    const float* __restrict__ bof,
    float* __restrict__ Out)
{
    __shared__ __attribute__((aligned(16))) _Float16 sm_v[64 * 192];  // 24576 B
    __shared__ __attribute__((aligned(16))) _Float16 sm_u[64 * 192];  // 24576 B
    __shared__ __attribute__((aligned(16))) _Float16 sm_w[192 * 40];  // 15360 B

    const int t = threadIdx.x;
    const int bs = blockIdx.x >> 3;
    const int chunk = blockIdx.x & 7;
    const int b = bs >> 6, s = bs & 63;
    const int l0 = chunk * 64;
    const int w = t >> 6, lane = t & 63;
    const int quad = lane >> 4, n16 = lane & 15;

    // ---- stage V chunk: f32 -> f16, transpose to [l][c] swizzled ----------
    {
        const int tx = t & 15, rp = t >> 4;              // rp 0..31
        h2* smv2 = (h2*)sm_v;                            // dword granularity
#pragma unroll
        for (int i = 0; i < 3; ++i) {
            int cp = i * 32 + rp;                        // c = 2cp, 2cp+1
            const float* vp = V + ((size_t)(b * C_ + 2 * cp) * S_ + s) * L_ + l0 + tx * 4;
            f4 x0 = *(const f4*)vp;
            f4 x1 = *(const f4*)(vp + S_ * L_);
#pragma unroll
            for (int k = 0; k < 4; ++k) {
                int l = tx * 4 + k;
                int dw = l * 96 + (((cp >> 2) ^ swz_l(l)) << 2) + (cp & 3);
                h2 hh; hh[0] = (_Float16)x0[k]; hh[1] = (_Float16)x1[k];
                smv2[dw] = hh;
            }
        }
    }

    // =================== GEMM1: v[o,l] = Wv @ V ============================
    f4 acc[3][2];
#pragma unroll
    for (int i = 0; i < 3; ++i)
#pragma unroll
        for (int j = 0; j < 2; ++j) acc[i][j] = (f4)0.f;

    for (int kt = 0; kt < 6; ++kt) {
        __syncthreads();
        {   // stage Wv k-tile: rows o x 32 c, pad-40 layout
            const unsigned int* src = (const unsigned int*)wvh;
            unsigned int* dst = (unsigned int*)sm_w;
#pragma unroll
            for (int i = 0; i < 6; ++i) {
                int d = t + i * 512;
                int r = d >> 4, cd = d & 15;
                dst[r * 20 + cd] = src[r * 96 + kt * 16 + cd];
            }
        }
        __syncthreads();

        h8 bfr[2];
#pragma unroll
        for (int j = 0; j < 2; ++j) {
            int l = (w >> 2) * 32 + j * 16 + n16;
            bfr[j] = *(const h8*)(sm_v + l * 192 + ((((kt * 4 + quad)) ^ swz_l(l)) << 3));
        }
#pragma unroll
        for (int i = 0; i < 3; ++i) {
            int o = (w & 3) * 48 + i * 16 + n16;
            h8 afr = *(const h8*)(sm_w + o * 40 + quad * 8);
#pragma unroll
            for (int j = 0; j < 2; ++j)
                acc[i][j] = __builtin_amdgcn_mfma_f32_16x16x32_f16(afr, bfr[j], acc[i][j], 0, 0, 0);
        }
    }

    // ---- epilogue 1: u = ctx * relu(v + bv) -> sm_u [l][o] swizzled -------
#pragma unroll
    for (int i = 0; i < 3; ++i) {
        int o0 = (w & 3) * 48 + i * 16 + quad * 4;
        f4 cx = *(const f4*)(ctxb + (size_t)bs * C_ + o0);
        f4 bv = *(const f4*)(bvf + o0);
#pragma unroll
        for (int j = 0; j < 2; ++j) {
            int l = (w >> 2) * 32 + j * 16 + n16;
            h4 uu;
#pragma unroll
            for (int r = 0; r < 4; ++r) {
                float v = acc[i][j][r] + bv[r];
                uu[r] = (_Float16)(fmaxf(v, 0.f) * cx[r]);
            }
            *(h4*)(sm_u + l * 192 + (((o0 >> 3) ^ swz_l(l)) << 3) + (o0 & 7)) = uu;
        }
    }

    // =================== GEMM2: out[l,p] = u^T @ Wo^T ======================
    f4 acc2[2][3];
#pragma unroll
    for (int i = 0; i < 2; ++i)
#pragma unroll
        for (int j = 0; j < 3; ++j) acc2[i][j] = (f4)0.f;

    for (int kt = 0; kt < 6; ++kt) {
        __syncthreads();
        {   // stage Wo k-tile: rows p x 32 o
            const unsigned int* src = (const unsigned int*)woh;
            unsigned int* dst = (unsigned int*)sm_w;
#pragma unroll
            for (int i = 0; i < 6; ++i) {
                int d = t + i * 512;
                int r = d >> 4, cd = d & 15;
                dst[r * 20 + cd] = src[r * 96 + kt * 16 + cd];
            }
        }
        __syncthreads();

        h8 afr2[2];
#pragma unroll
        for (int i = 0; i < 2; ++i) {
            int l = (w >> 2) * 32 + i * 16 + n16;
            afr2[i] = *(const h8*)(sm_u + l * 192 + ((((kt * 4 + quad)) ^ swz_l(l)) << 3));
        }
#pragma unroll
        for (int j = 0; j < 3; ++j) {
            int p = (w & 3) * 48 + j * 16 + n16;
            h8 bfr = *(const h8*)(sm_w + p * 40 + quad * 8);
#pragma unroll
            for (int i = 0; i < 2; ++i)
                acc2[i][j] = __builtin_amdgcn_mfma_f32_16x16x32_f16(afr2[i], bfr, acc2[i][j], 0, 0, 0);
        }
    }

    // ---- epilogue 2: + bo, float4 stores ----------------------------------
#pragma unroll
    for (int j = 0; j < 3; ++j) {
        int p = (w & 3) * 48 + j * 16 + n16;
        float bo = bof[p];
        float* obase = Out + ((size_t)(b * C_ + p) * S_ + s) * L_ + l0;
#pragma unroll
        for (int i = 0; i < 2; ++i) {
            int l = (w >> 2) * 32 + i * 16 + quad * 4;
            f4 ov = acc2[i][j];
            ov[0] += bo; ov[1] += bo; ov[2] += bo; ov[3] += bo;
            *(f4*)(obase + l) = ov;
        }
    }
}

extern "C" void kernel_launch(void* const* d_in, const int* in_sizes, int n_in,
                              void* d_out, int out_size, void* d_ws, size_t ws_size,
                              hipStream_t stream) {
    const float* Q  = (const float*)d_in[0];
    const float* K  = (const float*)d_in[1];
    const float* V  = (const float*)d_in[2];
    const float* W  = (const float*)d_in[3];
    const float* Bi = (const float*)d_in[4];
    const float* Wo = (const float*)d_in[5];
    const float* Bo = (const float*)d_in[6];
    float* Out = (float*)d_out;

    char* ws = (char*)d_ws;
    _Float16* wvh = (_Float16*)(ws);                 // 73728 B
    _Float16* woh = (_Float16*)(ws + 73728);         // 73728 B
    float*    bvf = (float*)(ws + 147456);           // 768 B
    float*    bof = (float*)(ws + 148224);           // 768 B
    float*    pbuf = (float*)(ws + 148992);          // 524288 B
    float*    kbar = (float*)(ws + 673280);          // 196608 B
    float*    ctxb = (float*)(ws + 869888);          // 196608 B -> end 1066496

    k_prep  <<<dim3(145),      dim3(512), 0, stream>>>(W, Bi, Wo, Bo, wvh, woh, bvf, bof);
    k1_qsoft<<<dim3(B_ * S_),  dim3(512), 0, stream>>>(Q, W, pbuf);
    k2_kbar <<<dim3(B_*S_*6),  dim3(256), 0, stream>>>(K, pbuf, kbar);
    k3_ctx  <<<dim3(B_ * S_),  dim3(192), 0, stream>>>(W, Bi, kbar, ctxb);
    k_main  <<<dim3(B_*S_*8),  dim3(512), 0, stream>>>(V, wvh, woh, ctxb, bvf, bof, Out);
}